// Round 8
// baseline (1010.843 us; speedup 1.0000x reference)
//
#include <hip/hip_runtime.h>
#include <stdint.h>

#define NPIX   (16 * 512 * 512)   // 4,194,304
#define IMG    (512 * 512)
#define NB     16

#define CORE   64
#define HALO   8
#define KIT    8      // iterations per round; 200 = 25 * 8
#define NROUND 25
#define TBW    92     // boundary-row LDS stride (words)
#define ES     83     // edge-column LDS stride (int2)

#define BM_WORDS  (NPIX / 32)     // 131072 words = 512 KB per bitmap replica
#define NREP      8               // bitmap replicas (spread same-word atomics)
#define MAX3(a, b, c) max(max((a), (b)), (c))

// ---------- global max of predict (float4, 16 px/thread) ----------
__global__ __launch_bounds__(256) void k_max(const float4* __restrict__ p, unsigned int* umax) {
    unsigned int m = 0;
    int base = blockIdx.x * 1024;
#pragma unroll
    for (int k = 0; k < 4; ++k) {
        float4 v = p[base + k * 256 + threadIdx.x];
        m = max(m, __float_as_uint(v.x));
        m = max(m, __float_as_uint(v.y));
        m = max(m, __float_as_uint(v.z));
        m = max(m, __float_as_uint(v.w));
    }
    for (int o = 32; o > 0; o >>= 1)
        m = max(m, (unsigned int)__shfl_down(m, o, 64));
    __shared__ unsigned int sm[4];
    int lane = threadIdx.x & 63, w = threadIdx.x >> 6;
    if (lane == 0) sm[w] = m;
    __syncthreads();
    if (threadIdx.x == 0)
        atomicMax(umax, max(max(sm[0], sm[1]), max(sm[2], sm[3])));
}

// ---------- init labels + fused dice partials (float4, 16 px/thread) ----------
__global__ __launch_bounds__(256) void k_init(const float4* __restrict__ pr4,
                                              const float4* __restrict__ tg4,
                                              const unsigned int* __restrict__ umax,
                                              int4* __restrict__ lab4,
                                              float* __restrict__ num, float* __restrict__ den) {
    const float thr = __uint_as_float(*umax) * 0.5f;
    float sn = 0.f, sd = 0.f;
    int base = blockIdx.x * 1024;
#pragma unroll
    for (int k = 0; k < 4; ++k) {
        int i4 = base + k * 256 + threadIdx.x;
        float4 p = pr4[i4], t = tg4[i4];
        int pix = i4 * 4;
        int4 L;
        L.x = (p.x > thr) ? pix     : -1;
        L.y = (p.y > thr) ? pix + 1 : -1;
        L.z = (p.z > thr) ? pix + 2 : -1;
        L.w = (p.w > thr) ? pix + 3 : -1;
        lab4[i4] = L;
        sn += p.x * t.x + p.y * t.y + p.z * t.z + p.w * t.w;
        sd += p.x * p.x + p.y * p.y + p.z * p.z + p.w * p.w
            + t.x * t.x + t.y * t.y + t.z * t.z + t.w * t.w;
    }
    for (int o = 32; o > 0; o >>= 1) {
        sn += __shfl_down(sn, o, 64);
        sd += __shfl_down(sd, o, 64);
    }
    __shared__ float wn[4], wd[4];
    int lane = threadIdx.x & 63, w = threadIdx.x >> 6;
    if (lane == 0) { wn[w] = sn; wd[w] = sd; }
    __syncthreads();
    if (threadIdx.x == 0) {
        int b = blockIdx.x >> 6;
        atomicAdd(&num[b * 32], wn[0] + wn[1] + wn[2] + wn[3]);
        atomicAdd(&den[b * 32], wd[0] + wd[1] + wd[2] + wd[3]);
    }
}

#define STEP(j) do {                                                           \
        int4 col;                                                              \
        col.x = MAX3(A.x, B.x, C.x);                                           \
        col.y = MAX3(A.y, B.y, C.y);                                           \
        col.z = MAX3(A.z, B.z, C.z);                                           \
        col.w = MAX3(A.w, B.w, C.w);                                           \
        int cl = MAX3(Al, Bl, Cl);                                             \
        int cr = MAX3(Ar, Br, Cr);                                             \
        int4 n;                                                                \
        n.x = MAX3(cl,    col.x, col.y) | (B.x >> 31);  /* bg stays -1 */      \
        n.y = MAX3(col.x, col.y, col.z) | (B.y >> 31);                         \
        n.z = MAX3(col.y, col.z, col.w) | (B.z >> 31);                         \
        n.w = MAX3(col.z, col.w, cr)    | (B.w >> 31);                         \
        A = B; Al = Bl; Ar = Br;                                               \
        B = C; Bl = Cl; Br = Cr;                                               \
        O[j] = n;                                                              \
    } while (0)

// ---------- persistent propagation: 1 launch, 25 rounds x 8 fused iterations ----------
// 1024 blocks, all co-resident (22.7 KB LDS -> >=4 blocks/CU). Core strips live in
// registers across rounds; only halo strips reload. Cross-block exchange: ring publish
// with agent-scope atomic stores, monotonic flags (spin only on 8 neighbors), halo
// refill with agent-scope atomic loads (bypass stale per-XCD L2).
__global__ __launch_bounds__(256, 4) void k_prop_persist(int* __restrict__ bufA,
                                                         int* __restrict__ bufB,
                                                         int* __restrict__ flags) {
    __shared__ int  Tb[22 * TBW];
    __shared__ int2 E[22 * ES];
    const int tid  = threadIdx.x;
    const int blk  = blockIdx.x;
    const int bx   = blk & 7, by = (blk >> 3) & 7, bimg = blk >> 6;
    const int gx0  = bx * CORE - HALO;
    const int gy0  = by * CORE - HALO;
    int* const base0 = bufA + bimg * IMG;
    int* const base1 = bufB + bimg * IMG;

    // sentinels: E rows 0/81 + cells 0/21 stay -1; Tb pad slots 0/21 stay -1
    for (int i = tid; i < 22 * ES; i += 256) E[i] = make_int2(-1, -1);
    if (tid < TBW) { Tb[tid] = -1; Tb[21 * TBW + tid] = -1; }

    const bool active = (tid < 200);        // 20 col-units x 10 row-units
    const int cu = tid % 20, ru = tid / 20;
    const int x0 = cu * 4;
    const int yr = ru * 8;
    const int gx = gx0 + x0;
    const bool coreT = active && ru >= 1 && ru <= 8 && cu >= 2 && cu <= 17;
    const bool haloT = active && !coreT;
    const bool ringT = coreT && (ru == 1 || ru == 8 || cu <= 3 || cu >= 16);

    int nbf = -1;                            // neighbor flag index for tid<8
    if (tid < 8) {
        const int dxs[8] = {-1, 0, 1, -1, 1, -1, 0, 1};
        const int dys[8] = {-1, -1, -1, 0, 0, 1, 1, 1};
        int nx = bx + dxs[tid], ny = by + dys[tid];
        if (nx >= 0 && nx < 8 && ny >= 0 && ny < 8) nbf = bimg * 64 + ny * 8 + nx;
    }

    int4 O[8];
    __syncthreads();                         // sentinel init visible

    for (int r = 1; r <= NROUND; ++r) {
        if (r == 1) {
            if (active) {                    // field from init labels (prior kernel)
#pragma unroll
                for (int j = 0; j < 8; ++j) {
                    int gy = gy0 + yr + j;
                    O[j] = (gy >= 0 && gy < 512 && gx >= 0 && gx <= 508)
                           ? *(const int4*)(base0 + (gy << 9) + gx)
                           : make_int4(-1, -1, -1, -1);
                }
            }
        } else {
            if (nbf >= 0) {                  // wait 8 neighbors >= r-1
                while (__hip_atomic_load(&flags[nbf], __ATOMIC_RELAXED,
                                         __HIP_MEMORY_SCOPE_AGENT) < r - 1)
                    __builtin_amdgcn_s_sleep(1);
            }
            __syncthreads();
            if (haloT) {                     // refill halo strip via coherent loads
                const int* src = ((r - 1) & 1) ? base1 : base0;
#pragma unroll
                for (int j = 0; j < 8; ++j) {
                    int gy = gy0 + yr + j;
                    if (gy >= 0 && gy < 512 && gx >= 0 && gx <= 508) {
                        unsigned long long v0 = __hip_atomic_load(
                            (const unsigned long long*)(src + (gy << 9) + gx),
                            __ATOMIC_RELAXED, __HIP_MEMORY_SCOPE_AGENT);
                        unsigned long long v1 = __hip_atomic_load(
                            (const unsigned long long*)(src + (gy << 9) + gx + 2),
                            __ATOMIC_RELAXED, __HIP_MEMORY_SCOPE_AGENT);
                        O[j].x = (int)v0; O[j].y = (int)(v0 >> 32);
                        O[j].z = (int)v1; O[j].w = (int)(v1 >> 32);
                    } else O[j] = make_int4(-1, -1, -1, -1);
                }
            }
        }
        // publish boundary rows + edge cols into LDS
        if (active) {
            *(int4*)&Tb[(2 * ru + 1) * TBW + x0] = O[0];
            *(int4*)&Tb[(2 * ru + 2) * TBW + x0] = O[7];
#pragma unroll
            for (int j = 0; j < 8; ++j)
                E[(cu + 1) * ES + yr + j + 1] = make_int2(O[j].x, O[j].w);
        }
        __syncthreads();

        for (int it = 0; it < KIT; ++it) {
            if (active) {
                int vl[10], vr[10];
#pragma unroll
                for (int j = 0; j < 10; ++j) {
                    vl[j] = E[cu * ES + yr + j].y;
                    vr[j] = E[(cu + 2) * ES + yr + j].x;
                }
                int4 A  = *(const int4*)&Tb[(2 * ru) * TBW + x0];
                int4 C8 = *(const int4*)&Tb[(2 * ru + 3) * TBW + x0];
                int4 B = O[0], C;
                int Al = vl[0], Ar = vr[0], Bl = vl[1], Br = vr[1], Cl, Cr;
#pragma unroll
                for (int j = 0; j < 8; ++j) {
                    C = (j < 7) ? O[j + 1] : C8;
                    Cl = vl[j + 2]; Cr = vr[j + 2];
                    STEP(j);
                }
            }
            __syncthreads();
            if (active) {
                *(int4*)&Tb[(2 * ru + 1) * TBW + x0] = O[0];
                *(int4*)&Tb[(2 * ru + 2) * TBW + x0] = O[7];
#pragma unroll
                for (int j = 0; j < 8; ++j)
                    E[(cu + 1) * ES + yr + j + 1] = make_int2(O[j].x, O[j].w);
            }
            __syncthreads();
        }

        if (r < NROUND) {
            if (ringT) {                     // publish core outer-8 ring (coherent stores)
                int* dst = (r & 1) ? base1 : base0;
#pragma unroll
                for (int j = 0; j < 8; ++j) {
                    int gy = gy0 + yr + j;
                    unsigned long long v0 = ((unsigned long long)(unsigned)O[j].y << 32) | (unsigned)O[j].x;
                    unsigned long long v1 = ((unsigned long long)(unsigned)O[j].w << 32) | (unsigned)O[j].z;
                    __hip_atomic_store((unsigned long long*)(dst + (gy << 9) + gx), v0,
                                       __ATOMIC_RELAXED, __HIP_MEMORY_SCOPE_AGENT);
                    __hip_atomic_store((unsigned long long*)(dst + (gy << 9) + gx + 2), v1,
                                       __ATOMIC_RELAXED, __HIP_MEMORY_SCOPE_AGENT);
                }
            }
            __syncthreads();                 // vmcnt drained per wave before flag
            if (tid == 0)
                __hip_atomic_store(&flags[blk], r, __ATOMIC_RELEASE, __HIP_MEMORY_SCOPE_AGENT);
        } else {
            if (coreT) {                     // final: full core to bufB for k_bits
#pragma unroll
                for (int j = 0; j < 8; ++j)
                    *(int4*)(base1 + ((gy0 + yr + j) << 9) + gx) = O[j];
            }
        }
    }
}

// ---------- presence bitmap: replicated (x8) + run-head + hash dedup + test-and-set ----------
__global__ __launch_bounds__(256) void k_bits(const int* __restrict__ lab,
                                              unsigned int* __restrict__ bm) {
    __shared__ unsigned int sk[1024];   // SoA: sk[j*256 + tid]
    __shared__ int slot[256];
    const int tid = threadIdx.x;
    const int i4 = blockIdx.x * 256 + tid;
    unsigned int* rep = bm + (blockIdx.x & (NREP - 1)) * BM_WORDS;
    int4 c = ((const int4*)lab)[i4];
    int pw = __shfl_up(c.w, 1, 64);
    unsigned int prevk;
    if ((tid & 63) == 0) {
        if (i4 == 0) prevk = ~0u;
        else { int pv = lab[i4 * 4 - 1]; prevk = (pv < 0) ? 0u : (unsigned int)pv; }
    } else {
        prevk = (pw < 0) ? 0u : (unsigned int)pw;
    }
    unsigned int k0 = (c.x < 0) ? 0u : (unsigned int)c.x;
    unsigned int k1 = (c.y < 0) ? 0u : (unsigned int)c.y;
    unsigned int k2 = (c.z < 0) ? 0u : (unsigned int)c.z;
    unsigned int k3 = (c.w < 0) ? 0u : (unsigned int)c.w;
    bool c0 = (k0 != prevk), c1 = (k1 != k0), c2 = (k2 != k1), c3 = (k3 != k2);
    sk[0 * 256 + tid] = k0;
    sk[1 * 256 + tid] = k1;
    sk[2 * 256 + tid] = k2;
    sk[3 * 256 + tid] = k3;
    if (c0) slot[k0 & 255] = tid * 4 + 0;
    if (c1) slot[k1 & 255] = tid * 4 + 1;
    if (c2) slot[k2 & 255] = tid * 4 + 2;
    if (c3) slot[k3 & 255] = tid * 4 + 3;
    __syncthreads();
#define SKAT(w) sk[((w) & 3) * 256 + ((w) >> 2)]
    if (c0) { int w = slot[k0 & 255]; if (w != tid * 4 + 0 && SKAT(w) == k0) c0 = false; }
    if (c1) { int w = slot[k1 & 255]; if (w != tid * 4 + 1 && SKAT(w) == k1) c1 = false; }
    if (c2) { int w = slot[k2 & 255]; if (w != tid * 4 + 2 && SKAT(w) == k2) c2 = false; }
    if (c3) { int w = slot[k3 & 255]; if (w != tid * 4 + 3 && SKAT(w) == k3) c3 = false; }
#undef SKAT
#define TSET(kk, cc) if (cc) {                                        \
        unsigned int word = rep[(kk) >> 5];                           \
        if (!((word >> ((kk) & 31)) & 1u))                            \
            atomicOr(&rep[(kk) >> 5], 1u << ((kk) & 31));             \
    }
    TSET(k0, c0); TSET(k1, c1); TSET(k2, c2); TSET(k3, c3);
#undef TSET
}

// ---------- popcount reduce over OR of replicas ----------
__global__ void k_popc(const unsigned int* __restrict__ bm, unsigned int* nuniq, int words) {
    unsigned int c = 0;
    for (int i = blockIdx.x * blockDim.x + threadIdx.x; i < words; i += gridDim.x * blockDim.x) {
        unsigned int w = 0;
#pragma unroll
        for (int r = 0; r < NREP; ++r) w |= bm[r * BM_WORDS + i];
        c += __popc(w);
    }
    for (int o = 32; o > 0; o >>= 1)
        c += __shfl_down(c, o, 64);
    __shared__ unsigned int sc[4];
    int lane = threadIdx.x & 63, w = threadIdx.x >> 6;
    if (lane == 0) sc[w] = c;
    __syncthreads();
    if (threadIdx.x == 0)
        atomicAdd(nuniq, sc[0] + sc[1] + sc[2] + sc[3]);
}

// ---------- epilogue ----------
__global__ void k_final(const unsigned int* __restrict__ nuniq,
                        const float* __restrict__ num, const float* __restrict__ den,
                        float* __restrict__ out) {
    float loss = 0.0f;
    for (int b = 0; b < NB; ++b)
        loss += 1.0f - (num[b * 32] + 1.0f) / (den[b * 32] + 1.0f);
    loss *= (1.0f / NB);
    float penalty = (float)(*nuniq) / (float)NB;
    if (penalty < 1.0f) penalty = (float)NB;   // jnp.where(penalty < 1, B, penalty)
    penalty = fminf(penalty, (float)NB);       // jnp.minimum(penalty, B)
    out[0] = loss * penalty;
}

extern "C" void kernel_launch(void* const* d_in, const int* in_sizes, int n_in,
                              void* d_out, int out_size, void* d_ws, size_t ws_size,
                              hipStream_t stream) {
    const float* predict = (const float*)d_in[0];
    const float* target  = (const float*)d_in[1];
    float* out = (float*)d_out;

    // workspace layout (no overlaps — flags got its own region; R7 bug was
    // den[448..511] colliding with flags[0..63]):
    //   +0    : umax, nuniq
    //   +256  : num[512]  (slot b*32, one 128B line per batch)   -> +2304
    //   +2304 : den[512]                                          -> +4352
    //   +8192 : flags[1024]                                       -> +12288
    //   +16384: labA (16 MB) | labB (16 MB); bm replicas alias labA after prop
    char* ws = (char*)d_ws;
    unsigned int* umax  = (unsigned int*)ws;
    unsigned int* nuniq = (unsigned int*)(ws + 4);
    float* num = (float*)(ws + 256);
    float* den = (float*)(ws + 2304);
    int* flags = (int*)(ws + 8192);
    int* labA = (int*)(ws + 16384);
    int* labB = labA + NPIX;
    unsigned int* bm = (unsigned int*)labA;           // reuse labA after prop (4 MB)

    hipMemsetAsync(ws, 0, 16384, stream);

    k_max<<<1024, 256, 0, stream>>>((const float4*)predict, umax);
    k_init<<<1024, 256, 0, stream>>>((const float4*)predict, (const float4*)target,
                                     umax, (int4*)labA, num, den);

    // single persistent launch: 1024 blocks (4/CU guaranteed resident), 200 iterations
    k_prop_persist<<<1024, 256, 0, stream>>>(labA, labB, flags);
    // final labels in labB; labA now free -> bitmap replicas live there
    hipMemsetAsync(bm, 0, (size_t)NREP * BM_WORDS * sizeof(unsigned int), stream);

    k_bits<<<NPIX / 1024, 256, 0, stream>>>(labB, bm);
    k_popc<<<512, 256, 0, stream>>>(bm, nuniq, BM_WORDS);
    k_final<<<1, 1, 0, stream>>>(nuniq, num, den, out);
}

// Round 9
// 632.772 us; speedup vs baseline: 1.5975x; 1.5975x over previous
//
#include <hip/hip_runtime.h>
#include <stdint.h>

#define NPIX   (16 * 512 * 512)   // 4,194,304
#define IMG    (512 * 512)
#define NB     16
#define ITERS  200

#define CORE   64
#define HALO   8
#define KIT    8      // fused iterations per launch; 200 = 25 * 8
#define TBW    92     // boundary-row LDS stride (words)
#define ES     83     // edge-column LDS stride (int2)

#define BM_WORDS  (NPIX / 32)     // 131072 words = 512 KB per bitmap replica
#define NREP      8               // bitmap replicas (spread same-word atomics)
#define MAX3(a, b, c) max(max((a), (b)), (c))

// ---------- global max of predict (float4, 16 px/thread) ----------
__global__ __launch_bounds__(256) void k_max(const float4* __restrict__ p, unsigned int* umax) {
    unsigned int m = 0;
    int base = blockIdx.x * 1024;
#pragma unroll
    for (int k = 0; k < 4; ++k) {
        float4 v = p[base + k * 256 + threadIdx.x];
        m = max(m, __float_as_uint(v.x));
        m = max(m, __float_as_uint(v.y));
        m = max(m, __float_as_uint(v.z));
        m = max(m, __float_as_uint(v.w));
    }
    for (int o = 32; o > 0; o >>= 1)
        m = max(m, (unsigned int)__shfl_down(m, o, 64));
    __shared__ unsigned int sm[4];
    int lane = threadIdx.x & 63, w = threadIdx.x >> 6;
    if (lane == 0) sm[w] = m;
    __syncthreads();
    if (threadIdx.x == 0)
        atomicMax(umax, max(max(sm[0], sm[1]), max(sm[2], sm[3])));
}

// ---------- init labels + fused dice partials (float4, 16 px/thread) ----------
__global__ __launch_bounds__(256) void k_init(const float4* __restrict__ pr4,
                                              const float4* __restrict__ tg4,
                                              const unsigned int* __restrict__ umax,
                                              int4* __restrict__ lab4,
                                              float* __restrict__ num, float* __restrict__ den) {
    const float thr = __uint_as_float(*umax) * 0.5f;
    float sn = 0.f, sd = 0.f;
    int base = blockIdx.x * 1024;
#pragma unroll
    for (int k = 0; k < 4; ++k) {
        int i4 = base + k * 256 + threadIdx.x;
        float4 p = pr4[i4], t = tg4[i4];
        int pix = i4 * 4;
        int4 L;
        L.x = (p.x > thr) ? pix     : -1;
        L.y = (p.y > thr) ? pix + 1 : -1;
        L.z = (p.z > thr) ? pix + 2 : -1;
        L.w = (p.w > thr) ? pix + 3 : -1;
        lab4[i4] = L;
        sn += p.x * t.x + p.y * t.y + p.z * t.z + p.w * t.w;
        sd += p.x * p.x + p.y * p.y + p.z * p.z + p.w * p.w
            + t.x * t.x + t.y * t.y + t.z * t.z + t.w * t.w;
    }
    for (int o = 32; o > 0; o >>= 1) {
        sn += __shfl_down(sn, o, 64);
        sd += __shfl_down(sd, o, 64);
    }
    __shared__ float wn[4], wd[4];
    int lane = threadIdx.x & 63, w = threadIdx.x >> 6;
    if (lane == 0) { wn[w] = sn; wd[w] = sd; }
    __syncthreads();
    if (threadIdx.x == 0) {
        int b = blockIdx.x >> 6;
        atomicAdd(&num[b * 32], wn[0] + wn[1] + wn[2] + wn[3]);
        atomicAdd(&den[b * 32], wd[0] + wd[1] + wd[2] + wd[3]);
    }
}

// ---------- fused 8-iteration propagation, register strips + hoisted mask ----------
// Thread (cu,ru) owns rows yr..yr+7, cols x0..x0+3 in registers (O[8]).
// Pixel sign is iteration-invariant (masked >= 0, bg == -1): M[8] precomputed once,
// inner loop is h | M (no per-iter ashr).
__global__ __launch_bounds__(256, 4) void k_prop8(const int* __restrict__ in,
                                                  int* __restrict__ out) {
    __shared__ int  Tb[22 * TBW];
    __shared__ int2 E[22 * ES];
    const int tid  = threadIdx.x;
    const int bimg = blockIdx.z;
    const int gx0  = blockIdx.x * CORE - HALO;
    const int gy0  = blockIdx.y * CORE - HALO;
    const int* img = in + bimg * IMG;

    // sentinels: E rows 0/81 + cells 0/21 stay -1; Tb pad slots 0/21 stay -1
    for (int i = tid; i < 22 * ES; i += 256) E[i] = make_int2(-1, -1);
    if (tid < TBW) { Tb[tid] = -1; Tb[21 * TBW + tid] = -1; }

    const bool active = (tid < 200);    // 20 col-units x 10 row-units
    const int cu = tid % 20, ru = tid / 20;
    const int x0 = cu * 4;
    const int yr = ru * 8;
    const int gx = gx0 + x0;
    int4 O[8], M[8];

    __syncthreads();

#define GROW(row, V, VL, VR) do {                                              \
        int _gy = gy0 + (row);                                                 \
        if (_gy >= 0 && _gy < 512) {                                           \
            const int* _p = img + (_gy << 9);                                  \
            V  = (gx >= 0 && gx <= 508) ? *(const int4*)(_p + gx)              \
                                        : make_int4(-1, -1, -1, -1);           \
            VL = (gx - 1 >= 0 && gx - 1 < 512) ? _p[gx - 1] : -1;              \
            VR = (gx + 4 >= 0 && gx + 4 < 512) ? _p[gx + 4] : -1;              \
        } else { V = make_int4(-1, -1, -1, -1); VL = -1; VR = -1; }            \
    } while (0)

#define STEPM(j) do {                                                          \
        int4 col;                                                              \
        col.x = MAX3(A.x, B.x, C.x);                                           \
        col.y = MAX3(A.y, B.y, C.y);                                           \
        col.z = MAX3(A.z, B.z, C.z);                                           \
        col.w = MAX3(A.w, B.w, C.w);                                           \
        int cl = MAX3(Al, Bl, Cl);                                             \
        int cr = MAX3(Ar, Br, Cr);                                             \
        int4 n;                                                                \
        n.x = MAX3(cl,    col.x, col.y) | M[j].x;   /* bg stays -1 */          \
        n.y = MAX3(col.x, col.y, col.z) | M[j].y;                              \
        n.z = MAX3(col.y, col.z, col.w) | M[j].z;                              \
        n.w = MAX3(col.z, col.w, cr)    | M[j].w;                              \
        A = B; Al = Bl; Ar = Br;                                               \
        B = C; Bl = Cl; Br = Cr;                                               \
        O[j] = n;                                                              \
    } while (0)

    // ---- iter 0: field from global; capture iteration-invariant mask ----
    if (active) {
        int4 A, B, C; int Al, Ar, Bl, Br, Cl, Cr;
        GROW(yr - 1, A, Al, Ar);
        GROW(yr,     B, Bl, Br);
#pragma unroll
        for (int j = 0; j < 8; ++j) {
            GROW(yr + j + 1, C, Cl, Cr);
            M[j].x = B.x >> 31;
            M[j].y = B.y >> 31;
            M[j].z = B.z >> 31;
            M[j].w = B.w >> 31;
            STEPM(j);
        }
        // publish boundary rows + edge cols for iter 1
        *(int4*)&Tb[(2 * ru + 1) * TBW + x0] = O[0];
        *(int4*)&Tb[(2 * ru + 2) * TBW + x0] = O[7];
#pragma unroll
        for (int j = 0; j < 8; ++j)
            E[(cu + 1) * ES + yr + j + 1] = make_int2(O[j].x, O[j].w);
    }
    __syncthreads();

    // ---- iters 1..7: own rows from registers, neighbors from Tb/E ----
    for (int it = 1; it < KIT; ++it) {
        if (active) {
            int vl[10], vr[10];
#pragma unroll
            for (int j = 0; j < 10; ++j) {                 // rows yr-1 .. yr+8
                vl[j] = E[cu * ES + yr + j].y;             // west neighbor's col x0-1
                vr[j] = E[(cu + 2) * ES + yr + j].x;       // east neighbor's col x0+4
            }
            int4 A  = *(const int4*)&Tb[(2 * ru) * TBW + x0];       // row yr-1
            int4 C8 = *(const int4*)&Tb[(2 * ru + 3) * TBW + x0];   // row yr+8
            int4 B = O[0], C;
            int Al = vl[0], Ar = vr[0], Bl = vl[1], Br = vr[1], Cl, Cr;
#pragma unroll
            for (int j = 0; j < 8; ++j) {
                C = (j < 7) ? O[j + 1] : C8;
                Cl = vl[j + 2]; Cr = vr[j + 2];
                STEPM(j);
            }
        }
        if (it < KIT - 1) {                // last iteration's publish is dead
            __syncthreads();               // WAR: all reads done before overwrite
            if (active) {
                *(int4*)&Tb[(2 * ru + 1) * TBW + x0] = O[0];
                *(int4*)&Tb[(2 * ru + 2) * TBW + x0] = O[7];
#pragma unroll
                for (int j = 0; j < 8; ++j)
                    E[(cu + 1) * ES + yr + j + 1] = make_int2(O[j].x, O[j].w);
            }
            __syncthreads();               // RAW: publish visible before next reads
        }
    }

    // ---- write 64x64 core to global from registers ----
    if (active && ru >= 1 && ru <= 8 && cu >= 2 && cu <= 17) {
        int* oimg = out + bimg * IMG;
        int gyb = blockIdx.y * CORE + (yr - HALO);
        int gxo = blockIdx.x * CORE + (x0 - HALO);
#pragma unroll
        for (int j = 0; j < 8; ++j)
            *(int4*)(oimg + ((gyb + j) << 9) + gxo) = O[j];
    }
#undef GROW
#undef STEPM
}

// ---------- presence bitmap: replicated (x8) + run-head + hash dedup + test-and-set ----------
__global__ __launch_bounds__(256) void k_bits(const int* __restrict__ lab,
                                              unsigned int* __restrict__ bm) {
    __shared__ unsigned int sk[1024];   // SoA: sk[j*256 + tid]
    __shared__ int slot[256];
    const int tid = threadIdx.x;
    const int i4 = blockIdx.x * 256 + tid;
    unsigned int* rep = bm + (blockIdx.x & (NREP - 1)) * BM_WORDS;
    int4 c = ((const int4*)lab)[i4];
    int pw = __shfl_up(c.w, 1, 64);
    unsigned int prevk;
    if ((tid & 63) == 0) {
        if (i4 == 0) prevk = ~0u;
        else { int pv = lab[i4 * 4 - 1]; prevk = (pv < 0) ? 0u : (unsigned int)pv; }
    } else {
        prevk = (pw < 0) ? 0u : (unsigned int)pw;
    }
    unsigned int k0 = (c.x < 0) ? 0u : (unsigned int)c.x;
    unsigned int k1 = (c.y < 0) ? 0u : (unsigned int)c.y;
    unsigned int k2 = (c.z < 0) ? 0u : (unsigned int)c.z;
    unsigned int k3 = (c.w < 0) ? 0u : (unsigned int)c.w;
    bool c0 = (k0 != prevk), c1 = (k1 != k0), c2 = (k2 != k1), c3 = (k3 != k2);
    sk[0 * 256 + tid] = k0;
    sk[1 * 256 + tid] = k1;
    sk[2 * 256 + tid] = k2;
    sk[3 * 256 + tid] = k3;
    if (c0) slot[k0 & 255] = tid * 4 + 0;
    if (c1) slot[k1 & 255] = tid * 4 + 1;
    if (c2) slot[k2 & 255] = tid * 4 + 2;
    if (c3) slot[k3 & 255] = tid * 4 + 3;
    __syncthreads();
#define SKAT(w) sk[((w) & 3) * 256 + ((w) >> 2)]
    if (c0) { int w = slot[k0 & 255]; if (w != tid * 4 + 0 && SKAT(w) == k0) c0 = false; }
    if (c1) { int w = slot[k1 & 255]; if (w != tid * 4 + 1 && SKAT(w) == k1) c1 = false; }
    if (c2) { int w = slot[k2 & 255]; if (w != tid * 4 + 2 && SKAT(w) == k2) c2 = false; }
    if (c3) { int w = slot[k3 & 255]; if (w != tid * 4 + 3 && SKAT(w) == k3) c3 = false; }
#undef SKAT
#define TSET(kk, cc) if (cc) {                                        \
        unsigned int word = rep[(kk) >> 5];                           \
        if (!((word >> ((kk) & 31)) & 1u))                            \
            atomicOr(&rep[(kk) >> 5], 1u << ((kk) & 31));             \
    }
    TSET(k0, c0); TSET(k1, c1); TSET(k2, c2); TSET(k3, c3);
#undef TSET
}

// ---------- popcount reduce over OR of replicas ----------
__global__ void k_popc(const unsigned int* __restrict__ bm, unsigned int* nuniq, int words) {
    unsigned int c = 0;
    for (int i = blockIdx.x * blockDim.x + threadIdx.x; i < words; i += gridDim.x * blockDim.x) {
        unsigned int w = 0;
#pragma unroll
        for (int r = 0; r < NREP; ++r) w |= bm[r * BM_WORDS + i];
        c += __popc(w);
    }
    for (int o = 32; o > 0; o >>= 1)
        c += __shfl_down(c, o, 64);
    __shared__ unsigned int sc[4];
    int lane = threadIdx.x & 63, w = threadIdx.x >> 6;
    if (lane == 0) sc[w] = c;
    __syncthreads();
    if (threadIdx.x == 0)
        atomicAdd(nuniq, sc[0] + sc[1] + sc[2] + sc[3]);
}

// ---------- epilogue ----------
__global__ void k_final(const unsigned int* __restrict__ nuniq,
                        const float* __restrict__ num, const float* __restrict__ den,
                        float* __restrict__ out) {
    float loss = 0.0f;
    for (int b = 0; b < NB; ++b)
        loss += 1.0f - (num[b * 32] + 1.0f) / (den[b * 32] + 1.0f);
    loss *= (1.0f / NB);
    float penalty = (float)(*nuniq) / (float)NB;
    if (penalty < 1.0f) penalty = (float)NB;   // jnp.where(penalty < 1, B, penalty)
    penalty = fminf(penalty, (float)NB);       // jnp.minimum(penalty, B)
    out[0] = loss * penalty;
}

extern "C" void kernel_launch(void* const* d_in, const int* in_sizes, int n_in,
                              void* d_out, int out_size, void* d_ws, size_t ws_size,
                              hipStream_t stream) {
    const float* predict = (const float*)d_in[0];
    const float* target  = (const float*)d_in[1];
    float* out = (float*)d_out;

    // workspace layout (disjoint regions):
    //   +0    : umax, nuniq
    //   +256  : num[512]  (slot b*32, one 128B line per batch)
    //   +2304 : den[512]
    //   +16384: labA (16 MB) | labB (16 MB); bm replicas alias labA after prop
    char* ws = (char*)d_ws;
    unsigned int* umax  = (unsigned int*)ws;
    unsigned int* nuniq = (unsigned int*)(ws + 4);
    float* num = (float*)(ws + 256);
    float* den = (float*)(ws + 2304);
    int* labA = (int*)(ws + 16384);
    int* labB = labA + NPIX;
    unsigned int* bm = (unsigned int*)labA;   // reuse labA after prop (4 MB)

    hipMemsetAsync(ws, 0, 16384, stream);

    k_max<<<1024, 256, 0, stream>>>((const float4*)predict, umax);
    k_init<<<1024, 256, 0, stream>>>((const float4*)predict, (const float4*)target,
                                     umax, (int4*)labA, num, den);

    dim3 pb(256, 1, 1), pg(8, 8, 16);   // 64x64 core tiles
    int* a = labA;
    int* b = labB;
    for (int it = 0; it < ITERS / KIT; ++it) {   // 25 launches x 8 fused iters
        k_prop8<<<pg, pb, 0, stream>>>(a, b);
        int* t = a; a = b; b = t;
    }
    // 25 launches (odd) -> final labels in labB == a; labA free for bitmap
    hipMemsetAsync(bm, 0, (size_t)NREP * BM_WORDS * sizeof(unsigned int), stream);

    k_bits<<<NPIX / 1024, 256, 0, stream>>>(a, bm);
    k_popc<<<512, 256, 0, stream>>>(bm, nuniq, BM_WORDS);
    k_final<<<1, 1, 0, stream>>>(nuniq, num, den, out);
}